// Round 3
// baseline (4490.547 us; speedup 1.0000x reference)
//
#include <hip/hip_runtime.h>
#include <stdint.h>

// RNN_6725918786207: 2-layer tanh RNN. B=64, T=512, D_IN=64, D_MODEL=512, D_OUT=64.
// Round 3: recurrence moved to MFMA (16x16x32 f16). 16 WGs x 4 batches, batch rows
// duplicated 4x in the M dimension (A row m reads h[m&3] -- LDS same-address dup is
// free, output rows duplicated, epilogue quad q extracts batch q). Whh resident as
// fragment-ordered tiles: 12 k-tiles in 384 VGPRs/lane + 4 k-tiles in 128 KiB LDS.
// One barrier/step, h double-buffered in 8.4 KiB LDS.
// X is produced in transposed [grp16][t][n][4batch] f16 layout by k_gemm_x so the
// rnn reads x_t as 8 coalesced dwordx2 per lane.

typedef unsigned int u32;
typedef unsigned short u16;
typedef _Float16 f16;
typedef _Float16 v8h __attribute__((ext_vector_type(8)));
typedef float    v4f __attribute__((ext_vector_type(4)));

#define T_STEPS 512
#define DM 512
#define BATCH 64

// ---------- small helpers ----------
__device__ __forceinline__ float f16lo(u32 u) {
    u16 s = (u16)(u & 0xffffu); f16 h; __builtin_memcpy(&h, &s, 2); return (float)h;
}
__device__ __forceinline__ float f16hi(u32 u) {
    u16 s = (u16)(u >> 16); f16 h; __builtin_memcpy(&h, &s, 2); return (float)h;
}
__device__ __forceinline__ u32 packh2(float lo, float hi) {
    f16 a = (f16)lo, b = (f16)hi; u16 ua, ub;
    __builtin_memcpy(&ua, &a, 2); __builtin_memcpy(&ub, &b, 2);
    return (u32)ua | ((u32)ub << 16);
}
__device__ __forceinline__ float tanh_fast(float z) {
    float e = __expf(2.0f * z);
    return 1.0f - 2.0f / (e + 1.0f);
}

// ---------- prep kernels ----------
__global__ void k_cast_f16(const float* __restrict__ src, f16* __restrict__ dst, int n) {
    int i = blockIdx.x * blockDim.x + threadIdx.x;
    if (i < n) dst[i] = (f16)src[i];
}

// Whh [512][512] fp32 (k-major rows) -> fragment-ordered f16:
// Wf[kt][nt][lane][j] = W[kt*32 + (lane>>4)*8 + j][nt*16 + (lane&15)]
// (B-operand layout of mfma_f32_16x16x32_f16: lane holds B[k=quad*8+j][n=lane&15])
__global__ void k_pack_frag(const float* __restrict__ W, uint4* __restrict__ Wf) {
    int i = blockIdx.x * blockDim.x + threadIdx.x;   // 32768 = 16*32*64
    int kt = i >> 11, nt = (i >> 6) & 31, l = i & 63;
    int col = nt * 16 + (l & 15);
    int k0 = kt * 32 + (l >> 4) * 8;
    f16 v[8];
    #pragma unroll
    for (int j = 0; j < 8; ++j) v[j] = (f16)W[(size_t)(k0 + j) * DM + col];
    uint4 o; __builtin_memcpy(&o, v, 16);
    Wf[i] = o;
}

// src fp32 [R][C] -> dst fp16 [C][R]
__global__ void k_transpose_f16(const float* __restrict__ src, f16* __restrict__ dst, int R, int C) {
    int i = blockIdx.x * blockDim.x + threadIdx.x;
    if (i < R * C) { int r = i / C, c = i % C; dst[c * R + r] = (f16)src[r * C + c]; }
}

__global__ void k_bias_sum(const float* a0, const float* b0, float* o0,
                           const float* a1, const float* b1, float* o1) {
    int i = blockIdx.x * blockDim.x + threadIdx.x;
    if (i < DM) { o0[i] = a0[i] + b0[i]; o1[i] = a1[i] + b1[i]; }
}

// ---------- standard MFMA GEMM (row-major A rows = b*T+t), fp32 out ----------
__global__ __launch_bounds__(256) void k_gemm(const f16* __restrict__ A, const f16* __restrict__ BT,
                                              float* __restrict__ Cout, const float* __restrict__ bias,
                                              int N, int K) {
    __shared__ f16 As[64][40];
    __shared__ f16 Bs[64][40];
    int tid = threadIdx.x;
    int mb = blockIdx.x, nb = blockIdx.y;
    int l = tid & 63, w = tid >> 6;
    int q = l >> 4, mr = l & 15;
    int sr = tid >> 2;
    int ko = (tid & 3) * 8;
    const f16* gA = A + (size_t)(mb * 64 + sr) * K + ko;
    const f16* gB = BT + (size_t)(nb * 64 + sr) * K + ko;

    v4f acc[4];
    #pragma unroll
    for (int nt = 0; nt < 4; ++nt) acc[nt] = (v4f){0.f, 0.f, 0.f, 0.f};

    for (int kt = 0; kt < K; kt += 32) {
        *(uint4*)&As[sr][ko] = *(const uint4*)(gA + kt);
        *(uint4*)&Bs[sr][ko] = *(const uint4*)(gB + kt);
        __syncthreads();
        v8h a = *(const v8h*)&As[w * 16 + mr][q * 8];
        #pragma unroll
        for (int nt = 0; nt < 4; ++nt) {
            v8h b = *(const v8h*)&Bs[nt * 16 + mr][q * 8];
            acc[nt] = __builtin_amdgcn_mfma_f32_16x16x32_f16(a, b, acc[nt], 0, 0, 0);
        }
        __syncthreads();
    }

    int row0 = mb * 64 + w * 16 + q * 4;
    #pragma unroll
    for (int nt = 0; nt < 4; ++nt) {
        int col = nb * 64 + nt * 16 + mr;
        float bv = bias[col];
        #pragma unroll
        for (int r = 0; r < 4; ++r)
            Cout[(size_t)(row0 + r) * N + col] = acc[nt][r] + bv;
    }
}

// ---------- X-producing GEMM: A read t-major (tile mb = t, in-tile row = batch b),
// output written to Xt4 layout [b>>2][t][col][b&3] f16, packed dwordx2 ----------
__global__ __launch_bounds__(256) void k_gemm_x(const f16* __restrict__ A, const f16* __restrict__ BT,
                                                f16* __restrict__ Xt, const float* __restrict__ bias,
                                                int K) {
    __shared__ f16 As[64][40];
    __shared__ f16 Bs[64][40];
    int tid = threadIdx.x;
    int mb = blockIdx.x, nb = blockIdx.y;   // mb = t (0..511), nb = n-block (0..7)
    int l = tid & 63, w = tid >> 6;
    int q = l >> 4, mr = l & 15;
    int sr = tid >> 2;                      // = batch b for A staging
    int ko = (tid & 3) * 8;
    const f16* gA = A + ((size_t)sr * T_STEPS + mb) * K + ko;   // A[b][t][k] row-major
    const f16* gB = BT + (size_t)(nb * 64 + sr) * K + ko;

    v4f acc[4];
    #pragma unroll
    for (int nt = 0; nt < 4; ++nt) acc[nt] = (v4f){0.f, 0.f, 0.f, 0.f};

    for (int kt = 0; kt < K; kt += 32) {
        *(uint4*)&As[sr][ko] = *(const uint4*)(gA + kt);
        *(uint4*)&Bs[sr][ko] = *(const uint4*)(gB + kt);
        __syncthreads();
        v8h a = *(const v8h*)&As[w * 16 + mr][q * 8];
        #pragma unroll
        for (int nt = 0; nt < 4; ++nt) {
            v8h b = *(const v8h*)&Bs[nt * 16 + mr][q * 8];
            acc[nt] = __builtin_amdgcn_mfma_f32_16x16x32_f16(a, b, acc[nt], 0, 0, 0);
        }
        __syncthreads();
    }

    // in-tile rows = batches w*16 + q*4 + r; t = mb. Pack r=0..3 -> dwordx2.
    uint2* Xo = (uint2*)Xt;
    int grp = w * 4 + q;                    // = b>>2
    #pragma unroll
    for (int nt = 0; nt < 4; ++nt) {
        int col = nb * 64 + nt * 16 + mr;
        float bv = bias[col];
        u32 p01 = packh2(acc[nt][0] + bv, acc[nt][1] + bv);
        u32 p23 = packh2(acc[nt][2] + bv, acc[nt][3] + bv);
        Xo[((size_t)grp * T_STEPS + mb) * DM + col] = make_uint2(p01, p23);
    }
}

// ---------- MFMA recurrence ----------
// Grid = 16 WGs; WG bg handles batches 4bg..4bg+3. 256 threads, 1 wave/SIMD.
// A (h) rows duplicated: row m <- h[m&3]. B (Whh) frag-resident:
// kt 0..11 in regs (384 VGPRs/lane), kt 12..15 in 128 KiB LDS.
__global__ __launch_bounds__(256, 1) void k_rnn(const uint4* __restrict__ Wf,
                                                const f16* __restrict__ Xt,
                                                f16* __restrict__ H) {
    __shared__ uint4 Blds[4 * 32 * 64];     // 128 KiB: kt 12..15 fragment-ordered
    __shared__ f16 hbuf[2][4][528];         // double-buffered h, rows padded (8.25 KiB)

    int bg = blockIdx.x, tid = threadIdx.x;
    int w = tid >> 6, l = tid & 63;
    int l15 = l & 15, q = l >> 4, b3 = l & 3;

    for (int i = tid; i < 4 * 32 * 64; i += 256) Blds[i] = Wf[12 * 32 * 64 + i];

    const v8h* WfH = (const v8h*)Wf;
    v8h breg[12][8];
    #pragma unroll
    for (int kt = 0; kt < 12; ++kt)
        #pragma unroll
        for (int j = 0; j < 8; ++j)
            breg[kt][j] = WfH[(size_t)(kt * 32 + w * 8 + j) * 64 + l];

    for (int i = tid; i < 2 * 4 * 528; i += 256) ((f16*)hbuf)[i] = (f16)0.f;
    __syncthreads();

    const v8h* BldsH = (const v8h*)Blds;
    int cur = 0;
    #pragma unroll 1
    for (int t = 0; t < T_STEPS; ++t) {
        // x_t for this step: Xt4[bg][t][n][r], lane reads 4 f16 (r=0..3) per n-tile
        const uint2* xp = (const uint2*)(Xt + (size_t)(bg * T_STEPS + t) * 2048);
        uint2 xv[8];
        #pragma unroll
        for (int j = 0; j < 8; ++j) xv[j] = xp[(w * 8 + j) * 16 + l15];

        v4f C[8];
        #pragma unroll
        for (int j = 0; j < 8; ++j) C[j] = (v4f){0.f, 0.f, 0.f, 0.f};

        const f16* hrow = &hbuf[cur][b3][0];    // A row m reads h[m&3] (dup broadcast)
        #pragma unroll
        for (int kt = 0; kt < 16; ++kt) {
            v8h a = *(const v8h*)(hrow + kt * 32 + q * 8);
            if (kt < 12) {
                #pragma unroll
                for (int j = 0; j < 8; ++j)
                    C[j] = __builtin_amdgcn_mfma_f32_16x16x32_f16(a, breg[kt][j], C[j], 0, 0, 0);
            } else {
                #pragma unroll
                for (int j = 0; j < 8; ++j) {
                    v8h bl = BldsH[(size_t)((kt - 12) * 32 + w * 8 + j) * 64 + l];
                    C[j] = __builtin_amdgcn_mfma_f32_16x16x32_f16(a, bl, C[j], 0, 0, 0);
                }
            }
        }

        // Epilogue: quad q extracts batch q's row (C reg r=q), adds x, tanh, writes
        // h to LDS row q and H (row-major) for batch bg*4+q. Branchless.
        int nxt = cur ^ 1;
        f16* hw = &hbuf[nxt][0][0];
        f16* Hb = H + ((size_t)(bg * 4) * T_STEPS + t) * DM;
        #pragma unroll
        for (int j = 0; j < 8; ++j) {
            float cA = (q & 2) ? C[j][2] : C[j][0];
            float cB = (q & 2) ? C[j][3] : C[j][1];
            float cq = (q & 1) ? cB : cA;
            u32 word = (q & 2) ? xv[j].y : xv[j].x;
            float xq = (q & 1) ? f16hi(word) : f16lo(word);
            f16 hv = (f16)tanh_fast(cq + xq);
            int n = (w * 8 + j) * 16 + l15;
            hw[q * 528 + n] = hv;                              // LDS h row q
            Hb[(size_t)q * (T_STEPS * DM) + n] = hv;           // global H, batch bg*4+q
        }
        __syncthreads();
        cur = nxt;
    }
}

// ---------- launch ----------
extern "C" void kernel_launch(void* const* d_in, const int* in_sizes, int n_in,
                              void* d_out, int out_size, void* d_ws, size_t ws_size,
                              hipStream_t stream) {
    (void)in_sizes; (void)n_in; (void)out_size; (void)ws_size;
    const float* data = (const float*)d_in[0];
    const float* Wih0 = (const float*)d_in[1];
    const float* bih0 = (const float*)d_in[2];
    const float* Whh0 = (const float*)d_in[3];
    const float* bhh0 = (const float*)d_in[4];
    const float* Wih1 = (const float*)d_in[5];
    const float* bih1 = (const float*)d_in[6];
    const float* Whh1 = (const float*)d_in[7];
    const float* bhh1 = (const float*)d_in[8];
    const float* Wout = (const float*)d_in[9];
    const float* bout = (const float*)d_in[10];

    char* ws = (char*)d_ws;
    // workspace layout (bytes); total ~101.7 MiB (same footprint as round 2)
    f16*   Xt   = (f16*)(ws + 0);                    // Xt4 [16][512][512][4] f16 = 33.5MB (X0/X1 shared)
    f16*   H0   = (f16*)(ws + 33554432);             // [64*512][512] f16 row-major
    f16*   H1   = (f16*)(ws + 67108864);             // [64*512][512] f16 row-major
    f16*   D16  = (f16*)(ws + 100663296);            // data f16 [64][512][64]
    uint4* Wf0  = (uint4*)(ws + 104857600);          // frag-ordered Whh0 (512KB)
    uint4* Wf1  = (uint4*)(ws + 105381888);          // frag-ordered Whh1 (512KB)
    f16*   WT0  = (f16*)(ws + 105906176);            // Wih0^T [512][64]
    f16*   WT1  = (f16*)(ws + 105971712);            // Wih1^T [512][512]
    f16*   WoT  = (f16*)(ws + 106496000);            // Wout^T [64][512]
    float* bias0 = (float*)(ws + 106561536);
    float* bias1 = (float*)(ws + 106563584);

    // prep
    k_cast_f16<<<8192, 256, 0, stream>>>(data, D16, BATCH * T_STEPS * 64);
    k_pack_frag<<<128, 256, 0, stream>>>(Whh0, Wf0);
    k_pack_frag<<<128, 256, 0, stream>>>(Whh1, Wf1);
    k_transpose_f16<<<128, 256, 0, stream>>>(Wih0, WT0, 64, 512);
    k_transpose_f16<<<1024, 256, 0, stream>>>(Wih1, WT1, 512, 512);
    k_transpose_f16<<<128, 256, 0, stream>>>(Wout, WoT, 512, 64);
    k_bias_sum<<<2, 256, 0, stream>>>(bih0, bhh0, bias0, bih1, bhh1, bias1);

    dim3 gX(512, 8);
    // X0 = data @ Wih0 + bias0  -> Xt4 layout
    k_gemm_x<<<gX, 256, 0, stream>>>(D16, WT0, Xt, bias0, 64);
    // layer-0 recurrence (MFMA)
    k_rnn<<<16, 256, 0, stream>>>(Wf0, Xt, H0);
    // X1 = H0 @ Wih1 + bias1 -> Xt4 layout
    k_gemm_x<<<gX, 256, 0, stream>>>(H0, WT1, Xt, bias1, 512);
    // layer-1 recurrence (MFMA)
    k_rnn<<<16, 256, 0, stream>>>(Wf1, Xt, H1);
    // OUT = H1 @ Wout + bout -> fp32 d_out (row = b*T + t)
    k_gemm<<<dim3(512, 1), 256, 0, stream>>>(H1, WoT, (float*)d_out, bout, 64, 512);
}

// Round 6
// 2870.916 us; speedup vs baseline: 1.5642x; 1.5642x over previous
//
#include <hip/hip_runtime.h>
#include <stdint.h>

// RNN_6725918786207: 2-layer tanh RNN. B=64, T=512, D_IN=64, D_MODEL=512, D_OUT=64.
// Round 6: k_rnn is INTRINSIC-ONLY MFMA (inline-asm MFMA produced order-independent
// ~5e-2 corruption in R4/R5 — un-modeled hazard windows inside INLINEASM). Weight
// residency is forced by empty volatile pins INSIDE the t-loop:
//   kt 0..7  -> "+a" pin (AGPR); MFMA intrinsics consume AGPRs directly (AV operand class)
//   kt 8..11 -> "+v" pin (arch VGPR)
//   kt 12..15-> 128 KiB LDS
// In-loop pins = loop-carried opaque defs: un-rematerializable, hoist-proof.
// A-fragments are loaded per-kt from LDS (R3 style) to keep arch pressure ~200/256.

typedef unsigned int u32;
typedef unsigned short u16;
typedef _Float16 f16;
typedef _Float16 v8h __attribute__((ext_vector_type(8)));
typedef float    v4f __attribute__((ext_vector_type(4)));

#define T_STEPS 512
#define DM 512
#define BATCH 64

// ---------- small helpers ----------
__device__ __forceinline__ float f16lo(u32 u) {
    u16 s = (u16)(u & 0xffffu); f16 h; __builtin_memcpy(&h, &s, 2); return (float)h;
}
__device__ __forceinline__ float f16hi(u32 u) {
    u16 s = (u16)(u >> 16); f16 h; __builtin_memcpy(&h, &s, 2); return (float)h;
}
__device__ __forceinline__ u32 packh2(float lo, float hi) {
    f16 a = (f16)lo, b = (f16)hi; u16 ua, ub;
    __builtin_memcpy(&ua, &a, 2); __builtin_memcpy(&ub, &b, 2);
    return (u32)ua | ((u32)ub << 16);
}
__device__ __forceinline__ float tanh_fast(float z) {
    float e = __expf(2.0f * z);
    return 1.0f - 2.0f / (e + 1.0f);
}

// ---------- prep kernels ----------
__global__ void k_cast_f16(const float* __restrict__ src, f16* __restrict__ dst, int n) {
    int i = blockIdx.x * blockDim.x + threadIdx.x;
    if (i < n) dst[i] = (f16)src[i];
}

// Whh [512][512] fp32 (k-major rows) -> fragment-ordered f16:
// Wf[kt][nt][lane][j] = W[kt*32 + (lane>>4)*8 + j][nt*16 + (lane&15)]
__global__ void k_pack_frag(const float* __restrict__ W, uint4* __restrict__ Wf) {
    int i = blockIdx.x * blockDim.x + threadIdx.x;   // 32768 = 16*32*64
    int kt = i >> 11, nt = (i >> 6) & 31, l = i & 63;
    int col = nt * 16 + (l & 15);
    int k0 = kt * 32 + (l >> 4) * 8;
    f16 v[8];
    #pragma unroll
    for (int j = 0; j < 8; ++j) v[j] = (f16)W[(size_t)(k0 + j) * DM + col];
    uint4 o; __builtin_memcpy(&o, v, 16);
    Wf[i] = o;
}

// src fp32 [R][C] -> dst fp16 [C][R]
__global__ void k_transpose_f16(const float* __restrict__ src, f16* __restrict__ dst, int R, int C) {
    int i = blockIdx.x * blockDim.x + threadIdx.x;
    if (i < R * C) { int r = i / C, c = i % C; dst[c * R + r] = (f16)src[r * C + c]; }
}

__global__ void k_bias_sum(const float* a0, const float* b0, float* o0,
                           const float* a1, const float* b1, float* o1) {
    int i = blockIdx.x * blockDim.x + threadIdx.x;
    if (i < DM) { o0[i] = a0[i] + b0[i]; o1[i] = a1[i] + b1[i]; }
}

// ---------- standard MFMA GEMM (row-major A rows = b*T+t), fp32 out ----------
__global__ __launch_bounds__(256) void k_gemm(const f16* __restrict__ A, const f16* __restrict__ BT,
                                              float* __restrict__ Cout, const float* __restrict__ bias,
                                              int N, int K) {
    __shared__ f16 As[64][40];
    __shared__ f16 Bs[64][40];
    int tid = threadIdx.x;
    int mb = blockIdx.x, nb = blockIdx.y;
    int l = tid & 63, w = tid >> 6;
    int q = l >> 4, mr = l & 15;
    int sr = tid >> 2;
    int ko = (tid & 3) * 8;
    const f16* gA = A + (size_t)(mb * 64 + sr) * K + ko;
    const f16* gB = BT + (size_t)(nb * 64 + sr) * K + ko;

    v4f acc[4];
    #pragma unroll
    for (int nt = 0; nt < 4; ++nt) acc[nt] = (v4f){0.f, 0.f, 0.f, 0.f};

    for (int kt = 0; kt < K; kt += 32) {
        *(uint4*)&As[sr][ko] = *(const uint4*)(gA + kt);
        *(uint4*)&Bs[sr][ko] = *(const uint4*)(gB + kt);
        __syncthreads();
        v8h a = *(const v8h*)&As[w * 16 + mr][q * 8];
        #pragma unroll
        for (int nt = 0; nt < 4; ++nt) {
            v8h b = *(const v8h*)&Bs[nt * 16 + mr][q * 8];
            acc[nt] = __builtin_amdgcn_mfma_f32_16x16x32_f16(a, b, acc[nt], 0, 0, 0);
        }
        __syncthreads();
    }

    int row0 = mb * 64 + w * 16 + q * 4;
    #pragma unroll
    for (int nt = 0; nt < 4; ++nt) {
        int col = nb * 64 + nt * 16 + mr;
        float bv = bias[col];
        #pragma unroll
        for (int r = 0; r < 4; ++r)
            Cout[(size_t)(row0 + r) * N + col] = acc[nt][r] + bv;
    }
}

// ---------- X-producing GEMM: tile mb = t, in-tile row = batch b;
// output in Xt4 layout [b>>2][t][col][b&3] f16 ----------
__global__ __launch_bounds__(256) void k_gemm_x(const f16* __restrict__ A, const f16* __restrict__ BT,
                                                f16* __restrict__ Xt, const float* __restrict__ bias,
                                                int K) {
    __shared__ f16 As[64][40];
    __shared__ f16 Bs[64][40];
    int tid = threadIdx.x;
    int mb = blockIdx.x, nb = blockIdx.y;   // mb = t (0..511), nb = n-block (0..7)
    int l = tid & 63, w = tid >> 6;
    int q = l >> 4, mr = l & 15;
    int sr = tid >> 2;                      // = batch b for A staging
    int ko = (tid & 3) * 8;
    const f16* gA = A + ((size_t)sr * T_STEPS + mb) * K + ko;   // A[b][t][k] row-major
    const f16* gB = BT + (size_t)(nb * 64 + sr) * K + ko;

    v4f acc[4];
    #pragma unroll
    for (int nt = 0; nt < 4; ++nt) acc[nt] = (v4f){0.f, 0.f, 0.f, 0.f};

    for (int kt = 0; kt < K; kt += 32) {
        *(uint4*)&As[sr][ko] = *(const uint4*)(gA + kt);
        *(uint4*)&Bs[sr][ko] = *(const uint4*)(gB + kt);
        __syncthreads();
        v8h a = *(const v8h*)&As[w * 16 + mr][q * 8];
        #pragma unroll
        for (int nt = 0; nt < 4; ++nt) {
            v8h b = *(const v8h*)&Bs[nt * 16 + mr][q * 8];
            acc[nt] = __builtin_amdgcn_mfma_f32_16x16x32_f16(a, b, acc[nt], 0, 0, 0);
        }
        __syncthreads();
    }

    uint2* Xo = (uint2*)Xt;
    int grp = w * 4 + q;                    // = b>>2
    #pragma unroll
    for (int nt = 0; nt < 4; ++nt) {
        int col = nb * 64 + nt * 16 + mr;
        float bv = bias[col];
        u32 p01 = packh2(acc[nt][0] + bv, acc[nt][1] + bv);
        u32 p23 = packh2(acc[nt][2] + bv, acc[nt][3] + bv);
        Xo[((size_t)grp * T_STEPS + mb) * DM + col] = make_uint2(p01, p23);
    }
}

// ---------- MFMA recurrence ----------
// Grid = 16 WGs; WG bg handles batches 4bg..4bg+3. 256 threads, 1 wave/SIMD.
// A (h) rows duplicated: row m <- h[m&3]. B (Whh) split:
//   kt 0..7 AGPR-pinned, kt 8..11 VGPR-pinned, kt 12..15 LDS. All MFMA intrinsics.
__global__ __launch_bounds__(256, 1) void k_rnn(const uint4* __restrict__ Wf,
                                                const f16* __restrict__ Xt,
                                                f16* __restrict__ H) {
    __shared__ uint4 Blds[4 * 32 * 64];     // 128 KiB: kt 12..15 fragment-ordered
    __shared__ f16 hbuf[2][4][528];         // double-buffered h, rows padded (8.25 KiB)

    int bg = blockIdx.x, tid = threadIdx.x;
    int w = tid >> 6, l = tid & 63;
    int l15 = l & 15, q = l >> 4, b3 = l & 3;

    for (int i = tid; i < 4 * 32 * 64; i += 256) Blds[i] = Wf[12 * 32 * 64 + i];

    const v8h* WfH = (const v8h*)Wf;
    // kt 0..7 -> AGPRs; kt 8..11 -> arch VGPRs. Loaded once; pinned every iteration.
    v8h ba[8][8];
    #pragma unroll
    for (int kt = 0; kt < 8; ++kt)
        #pragma unroll
        for (int j = 0; j < 8; ++j) {
            ba[kt][j] = WfH[(size_t)(kt * 32 + w * 8 + j) * 64 + l];
            asm volatile("" : "+a"(ba[kt][j]));
        }
    v8h bv[4][8];
    #pragma unroll
    for (int kt = 0; kt < 4; ++kt)
        #pragma unroll
        for (int j = 0; j < 8; ++j) {
            bv[kt][j] = WfH[(size_t)((8 + kt) * 32 + w * 8 + j) * 64 + l];
            asm volatile("" : "+v"(bv[kt][j]));
        }

    for (int i = tid; i < 2 * 4 * 528; i += 256) ((f16*)hbuf)[i] = (f16)0.f;
    __syncthreads();

    const v8h* BldsH = (const v8h*)Blds;
    int cur = 0;
    #pragma unroll 1
    for (int t = 0; t < T_STEPS; ++t) {
        // Re-pin weights each iteration: the asm is the loop-carried def, so the
        // allocator cannot rematerialize from global; class is forced (a / v).
        #pragma unroll
        for (int kt = 0; kt < 8; ++kt)
            #pragma unroll
            for (int j = 0; j < 8; ++j)
                asm volatile("" : "+a"(ba[kt][j]));
        #pragma unroll
        for (int kt = 0; kt < 4; ++kt)
            #pragma unroll
            for (int j = 0; j < 8; ++j)
                asm volatile("" : "+v"(bv[kt][j]));

        // x_t: Xt4[bg][t][n][r], lane reads r=0..3 packed per n-tile (dwordx2)
        const uint2* xp = (const uint2*)(Xt + (size_t)(bg * T_STEPS + t) * 2048);
        uint2 xv[8];
        #pragma unroll
        for (int j = 0; j < 8; ++j) xv[j] = xp[(w * 8 + j) * 16 + l15];

        const f16* hrow = &hbuf[cur][b3][0];    // A row m reads h[m&3] (broadcast)

        v4f C[8];
        #pragma unroll
        for (int j = 0; j < 8; ++j) C[j] = (v4f){0.f, 0.f, 0.f, 0.f};

        // kt 0..7: B AGPR-resident (intrinsic consumes AV operand directly)
        #pragma unroll
        for (int kt = 0; kt < 8; ++kt) {
            v8h a = *(const v8h*)(hrow + kt * 32 + q * 8);
            #pragma unroll
            for (int j = 0; j < 8; ++j)
                C[j] = __builtin_amdgcn_mfma_f32_16x16x32_f16(a, ba[kt][j], C[j], 0, 0, 0);
        }
        // kt 8..11: B arch-VGPR-resident
        #pragma unroll
        for (int kt = 0; kt < 4; ++kt) {
            v8h a = *(const v8h*)(hrow + (8 + kt) * 32 + q * 8);
            #pragma unroll
            for (int j = 0; j < 8; ++j)
                C[j] = __builtin_amdgcn_mfma_f32_16x16x32_f16(a, bv[kt][j], C[j], 0, 0, 0);
        }
        // kt 12..15: B from LDS
        #pragma unroll
        for (int kt = 0; kt < 4; ++kt) {
            v8h a = *(const v8h*)(hrow + (12 + kt) * 32 + q * 8);
            #pragma unroll
            for (int j = 0; j < 8; ++j) {
                v8h bl = BldsH[(size_t)(kt * 32 + w * 8 + j) * 64 + l];
                C[j] = __builtin_amdgcn_mfma_f32_16x16x32_f16(a, bl, C[j], 0, 0, 0);
            }
        }

        // Epilogue: quad q extracts batch q's row (C reg r=q), adds x, tanh,
        // writes h to LDS row q and global H for batch bg*4+q. Branchless.
        int nxt = cur ^ 1;
        f16* hw = &hbuf[nxt][0][0];
        f16* Hb = H + ((size_t)(bg * 4) * T_STEPS + t) * DM;
        #pragma unroll
        for (int j = 0; j < 8; ++j) {
            float cA = (q & 2) ? C[j][2] : C[j][0];
            float cB = (q & 2) ? C[j][3] : C[j][1];
            float cq = (q & 1) ? cB : cA;
            u32 word = (q & 2) ? xv[j].y : xv[j].x;
            float xq = (q & 1) ? f16hi(word) : f16lo(word);
            f16 hv = (f16)tanh_fast(cq + xq);
            int n = (w * 8 + j) * 16 + l15;
            hw[q * 528 + n] = hv;
            Hb[(size_t)q * (T_STEPS * DM) + n] = hv;
        }
        __syncthreads();
        cur = nxt;
    }
}

// ---------- launch ----------
extern "C" void kernel_launch(void* const* d_in, const int* in_sizes, int n_in,
                              void* d_out, int out_size, void* d_ws, size_t ws_size,
                              hipStream_t stream) {
    (void)in_sizes; (void)n_in; (void)out_size; (void)ws_size;
    const float* data = (const float*)d_in[0];
    const float* Wih0 = (const float*)d_in[1];
    const float* bih0 = (const float*)d_in[2];
    const float* Whh0 = (const float*)d_in[3];
    const float* bhh0 = (const float*)d_in[4];
    const float* Wih1 = (const float*)d_in[5];
    const float* bih1 = (const float*)d_in[6];
    const float* Whh1 = (const float*)d_in[7];
    const float* bhh1 = (const float*)d_in[8];
    const float* Wout = (const float*)d_in[9];
    const float* bout = (const float*)d_in[10];

    char* ws = (char*)d_ws;
    // workspace layout (bytes); total ~101.7 MiB
    f16*   Xt   = (f16*)(ws + 0);                    // Xt4 [16][512][512][4] f16 (X0/X1 shared)
    f16*   H0   = (f16*)(ws + 33554432);             // [64*512][512] f16 row-major
    f16*   H1   = (f16*)(ws + 67108864);             // [64*512][512] f16 row-major
    f16*   D16  = (f16*)(ws + 100663296);            // data f16 [64][512][64]
    uint4* Wf0  = (uint4*)(ws + 104857600);          // frag-ordered Whh0 (512KB)
    uint4* Wf1  = (uint4*)(ws + 105381888);          // frag-ordered Whh1 (512KB)
    f16*   WT0  = (f16*)(ws + 105906176);            // Wih0^T [512][64]
    f16*   WT1  = (f16*)(ws + 105971712);            // Wih1^T [512][512]
    f16*   WoT  = (f16*)(ws + 106496000);            // Wout^T [64][512]
    float* bias0 = (float*)(ws + 106561536);
    float* bias1 = (float*)(ws + 106563584);

    // prep
    k_cast_f16<<<8192, 256, 0, stream>>>(data, D16, BATCH * T_STEPS * 64);
    k_pack_frag<<<128, 256, 0, stream>>>(Whh0, Wf0);
    k_pack_frag<<<128, 256, 0, stream>>>(Whh1, Wf1);
    k_transpose_f16<<<128, 256, 0, stream>>>(Wih0, WT0, 64, 512);
    k_transpose_f16<<<1024, 256, 0, stream>>>(Wih1, WT1, 512, 512);
    k_transpose_f16<<<128, 256, 0, stream>>>(Wout, WoT, 512, 64);
    k_bias_sum<<<2, 256, 0, stream>>>(bih0, bhh0, bias0, bih1, bhh1, bias1);

    dim3 gX(512, 8);
    // X0 = data @ Wih0 + bias0  -> Xt4 layout
    k_gemm_x<<<gX, 256, 0, stream>>>(D16, WT0, Xt, bias0, 64);
    // layer-0 recurrence (MFMA)
    k_rnn<<<16, 256, 0, stream>>>(Wf0, Xt, H0);
    // X1 = H0 @ Wih1 + bias1 -> Xt4 layout
    k_gemm_x<<<gX, 256, 0, stream>>>(H0, WT1, Xt, bias1, 512);
    // layer-1 recurrence (MFMA)
    k_rnn<<<16, 256, 0, stream>>>(Wf1, Xt, H1);
    // OUT = H1 @ Wout + bout -> fp32 d_out (row = b*T + t)
    k_gemm<<<dim3(512, 1), 256, 0, stream>>>(H1, WoT, (float*)d_out, bout, 64, 512);
}